// Round 15
// baseline (2363.908 us; speedup 1.0000x reference)
//
#include <hip/hip_runtime.h>

#define HID 512
#define NB  256
#define TT  256
#define DIN 64
#define HBUF 131072                  // shorts per h panel (bf16 hi only)
#define SLOT_SH HBUF                 // slot = one panel (256 KB)
#define NSLOT 8                      // rotation depth; fence every NSLOT iters

typedef __attribute__((ext_vector_type(8))) short short8;
typedef __attribute__((ext_vector_type(4))) float f32x4;

__device__ __forceinline__ unsigned short f2bf(float f) {
    unsigned int u = __float_as_uint(f);
    u += 0x7FFF + ((u >> 16) & 1);
    return (unsigned short)(u >> 16);
}
__device__ __forceinline__ float bf2f(unsigned short h) {
    return __uint_as_float(((unsigned int)h) << 16);
}

// fast activations: v_exp_f32 + v_rcp_f32 (error ~1e-6, budget 7.2e-4)
__device__ __forceinline__ float fsig(float x) {
    return __builtin_amdgcn_rcpf(1.f + __expf(-x));
}
__device__ __forceinline__ float ftanh(float x) {
    return 1.f - 2.f * __builtin_amdgcn_rcpf(1.f + __expf(2.f * x));
}

// ---- LLC-coherent (cross-XCD) 4B access, explicit sc0/sc1 cache bits ----
__device__ __forceinline__ void st_u32_llc(unsigned* p, unsigned v) {
    asm volatile("global_store_dword %0, %1, off sc0 sc1" :: "v"(p), "v"(v) : "memory");
}
__device__ __forceinline__ unsigned ld_u32_llc(const unsigned* p) {
    unsigned v;
    asm volatile("global_load_dword %0, %1, off sc0 sc1\n\ts_waitcnt vmcnt(0)"
                 : "=v"(v) : "v"(p) : "memory");
    return v;
}

// h-A operand is single bf16: 2-term split (A.Bh + A.Bl)
#define MFMA2(acc, a, bh, bl)                                               \
    acc = __builtin_amdgcn_mfma_f32_16x16x32_bf16(a, bh, acc, 0, 0, 0);     \
    acc = __builtin_amdgcn_mfma_f32_16x16x32_bf16(a, bl, acc, 0, 0, 0);
// x-A operand keeps hi/lo: 3-term split
#define MFMA3(acc, ah, al, bh, bl)                                          \
    acc = __builtin_amdgcn_mfma_f32_16x16x32_bf16(ah, bh, acc, 0, 0, 0);    \
    acc = __builtin_amdgcn_mfma_f32_16x16x32_bf16(ah, bl, acc, 0, 0, 0);    \
    acc = __builtin_amdgcn_mfma_f32_16x16x32_bf16(al, bh, acc, 0, 0, 0);

// LDS layout (shorts): sW0 h/l: 18*512 each; sW1 h/l: 32*512 each; then sG floats
#define SW0_N 9216
#define SW1_N 16384
#define SG_F (2 * 128 * 17)          // [kh][128 rows][17]
#define LDS_BYTES ((SW0_N * 2 + SW1_N * 2) * 2 + SG_F * 4)

// packed 2-lane h store: lanes (l, l+1) hold adjacent j; even lane stores u32
__device__ __forceinline__ void store_h_pair(unsigned short* buf, size_t hoff,
                                             unsigned short v, int l) {
    unsigned int hv = (unsigned int)v;
    unsigned int up = __shfl_down(hv, 1);
    if ((l & 1) == 0)
        st_u32_llc((unsigned*)(buf + hoff), hv | (up << 16));
}

// wait: 128 lanes poll one flag each (LLC loads, no cache pollution), then barrier
__device__ __forceinline__ void flag_wait(unsigned* fset, int target) {
    if (threadIdx.x < 128) {
        unsigned* p = fset + threadIdx.x;
        while ((int)ld_u32_llc(p) < target) __builtin_amdgcn_s_sleep(2);
    }
    __syncthreads();
}

__global__ __launch_bounds__(512, 2) void lstm_persistent(
    const float* __restrict__ x,
    const float* __restrict__ Wih0, const float* __restrict__ Whh0,
    const float* __restrict__ bih0, const float* __restrict__ bhh0,
    const float* __restrict__ Wih1, const float* __restrict__ Whh1,
    const float* __restrict__ bih1, const float* __restrict__ bhh1,
    const float* __restrict__ headw, const float* __restrict__ headb,
    unsigned short* h0base, unsigned short* h1base,
    unsigned* gf, float* __restrict__ out)
{
    extern __shared__ unsigned short lds[];
    unsigned short* sW0h = lds;
    unsigned short* sW0l = sW0h + SW0_N;
    unsigned short* sW1h = sW0l + SW0_N;
    unsigned short* sW1l = sW1h + SW1_N;
    float* sG = (float*)(sW1l + SW1_N);          // [2][128][17]

    const int tid = threadIdx.x;
    const int l   = tid & 63;
    const int w   = tid >> 6;         // wave 0..7
    const int bt2 = w & 3;            // batch-pair tile (32 rows)
    const int kh  = w >> 2;           // K-half (0: k<256, 1: k>=256)
    const int bid = blockIdx.x;
    const int g   = bid & 1;          // batch group
    const int jb  = bid >> 1;         // j-block 0..127 (hidden units jb*4..jb*4+3)

    unsigned* f0g = gf + g * 128;            // layer0-done flags (this group)
    unsigned* f1g = gf + 256 + g * 128;      // layer1-done flags (this group)

    // ---- weight preload: fp32 -> hi/lo bf16 fragments in LDS ----
    const int r  = l & 15;
    const int ks = (l >> 4) * 8;
    const int n  = (r >> 2) * HID + jb * 4 + (r & 3);
    {
        for (int kt = w; kt < 18; kt += 8) {
            const float* src = (kt < 2) ? (Wih0 + (size_t)n * DIN + kt * 32 + ks)
                                        : (Whh0 + (size_t)n * HID + (kt - 2) * 32 + ks);
            float v[8];
            *(float4*)&v[0] = *(const float4*)src;
            *(float4*)&v[4] = *(const float4*)(src + 4);
            union { unsigned short u[8]; uint4 q; } ph, pl;
            #pragma unroll
            for (int e = 0; e < 8; ++e) {
                unsigned short h = f2bf(v[e]);
                ph.u[e] = h; pl.u[e] = f2bf(v[e] - bf2f(h));
            }
            *(uint4*)&sW0h[(kt * 64 + l) * 8] = ph.q;
            *(uint4*)&sW0l[(kt * 64 + l) * 8] = pl.q;
        }
        for (int kt = w; kt < 32; kt += 8) {
            const float* src = (kt < 16) ? (Wih1 + (size_t)n * HID + kt * 32 + ks)
                                         : (Whh1 + (size_t)n * HID + (kt - 16) * 32 + ks);
            float v[8];
            *(float4*)&v[0] = *(const float4*)src;
            *(float4*)&v[4] = *(const float4*)(src + 4);
            union { unsigned short u[8]; uint4 q; } ph, pl;
            #pragma unroll
            for (int e = 0; e < 8; ++e) {
                unsigned short h = f2bf(v[e]);
                ph.u[e] = h; pl.u[e] = f2bf(v[e] - bf2f(h));
            }
            *(uint4*)&sW1h[(kt * 64 + l) * 8] = ph.q;
            *(uint4*)&sW1l[(kt * 64 + l) * 8] = pl.q;
        }
    }

    float bias0[4], bias1[4];
    #pragma unroll
    for (int gi = 0; gi < 4; ++gi) {
        const int nn = gi * HID + jb * 4 + (l & 3);
        bias0[gi] = bih0[nn] + bhh0[nn];
        bias1[gi] = bih1[nn] + bhh1[nn];
    }
    float c0 = 0.f, c1 = 0.f;

    // epilogue geometry (each thread owns one (b_loc, jj))
    const int jj     = tid & 3;
    const int b_loc  = tid >> 2;      // 0..127 within group
    const int b_glob = g * 128 + b_loc;
    const int j_glob = jb * 4 + jj;
    const size_t hoff = ((((size_t)(b_glob >> 4)) * 16 + (j_glob >> 5)) * 64
                         + ((b_glob & 15) | (((j_glob >> 3) & 3) << 4))) * 8 + (j_glob & 7);
    const int t0 = g * 8 + bt2 * 2;   // first 16-row tile of this wave's 32 rows

    // x prefetch registers: this wave's x-kt == kh, 2 tiles
    const int xrow0 = g * 128 + bt2 * 32 + (l & 15);
    float xva[8], xvb[8];
    {
        const float* sa = x + ((size_t)xrow0 * TT + 0) * DIN + kh * 32 + ks;
        const float* sb = x + ((size_t)(xrow0 + 16) * TT + 0) * DIN + kh * 32 + ks;
        *(float4*)&xva[0] = *(const float4*)sa;
        *(float4*)&xva[4] = *(const float4*)(sa + 4);
        *(float4*)&xvb[0] = *(const float4*)sb;
        *(float4*)&xvb[4] = *(const float4*)(sb + 4);
    }

    __syncthreads();                 // weights ready

    // x-part B fragments pinned in VGPRs (kt = kh, static)
    const short8 bxh = *(const short8*)&sW0h[(kh * 64 + l) * 8];
    const short8 bxl = *(const short8*)&sW0l[(kh * 64 + l) * 8];

    float* sGk = sG + kh * (128 * 17);

    for (int it = 0; it <= TT; ++it) {
        // ---- wait 1: layer0 of it-1 done everywhere (signaled MID-iteration -> fast)
        flag_wait(f0g, it);

        // slot map: h0[t] -> slot t&7 ; h1[t] -> slot t&7
        const unsigned short* h0c = h0base + (size_t)((it + 7) & 7) * SLOT_SH;  // h0[it-1]
        unsigned short* h0n       = h0base + (size_t)(it & 7) * SLOT_SH;        // h0[it]
        const unsigned short* h1c = h1base + (size_t)((it + 6) & 7) * SLOT_SH;  // h1[it-2]
        unsigned short* h1n       = h1base + (size_t)((it + 7) & 7) * SLOT_SH;  // h1[it-1]

        f32x4 acc0[2][2] = {{{0.f,0.f,0.f,0.f},{0.f,0.f,0.f,0.f}},
                            {{0.f,0.f,0.f,0.f},{0.f,0.f,0.f,0.f}}};
        f32x4 acc1[2][2] = {{{0.f,0.f,0.f,0.f},{0.f,0.f,0.f,0.f}},
                            {{0.f,0.f,0.f,0.f},{0.f,0.f,0.f,0.f}}};

        // ---- hoisted h0[it-1] A-fragments: 2 tiles x 8 kt (K-half), batched (MLP);
        // ---- used by layer0 (W0hh) AND layer1 ys0-part (W1ih)
        short8 fAh[2][8];
        #pragma unroll
        for (int s = 0; s < 2; ++s)
            #pragma unroll
            for (int kt = 0; kt < 8; ++kt) {
                const size_t o = (((size_t)(t0 + s) * 16 + kh * 8 + kt) * 64 + l) * 8;
                fAh[s][kt] = *(const short8*)&h0c[o];
            }

        // ================= layer 0, t = it =================
        if (it < TT) {
            // x part (kt = kh): pinned B regs, 2 tiles
            {
                union { unsigned short u[8]; short8 s8; } ah, al;
                #pragma unroll
                for (int e = 0; e < 8; ++e) {
                    unsigned short h = f2bf(xva[e]);
                    ah.u[e] = h; al.u[e] = f2bf(xva[e] - bf2f(h));
                }
                MFMA3(acc0[0][kh], ah.s8, al.s8, bxh, bxl);
                #pragma unroll
                for (int e = 0; e < 8; ++e) {
                    unsigned short h = f2bf(xvb[e]);
                    ah.u[e] = h; al.u[e] = f2bf(xvb[e] - bf2f(h));
                }
                MFMA3(acc0[1][kh], ah.s8, al.s8, bxh, bxl);
            }
            // h part: 8 kt, B reused across 2 batch tiles
            #pragma unroll
            for (int kt = 0; kt < 8; ++kt) {
                const int ktg = kh * 8 + kt;
                short8 bh = *(const short8*)&sW0h[((ktg + 2) * 64 + l) * 8];
                short8 bl = *(const short8*)&sW0l[((ktg + 2) * 64 + l) * 8];
                MFMA2(acc0[0][kt & 1], fAh[0][kt], bh, bl);
                MFMA2(acc0[1][kt & 1], fAh[1][kt], bh, bl);
            }
            // write K-half partials to own sG half
            #pragma unroll
            for (int s = 0; s < 2; ++s)
                #pragma unroll
                for (int q = 0; q < 4; ++q)
                    sGk[(bt2 * 32 + s * 16 + (l >> 4) * 4 + q) * 17 + (l & 15)]
                        = acc0[s][0][q] + acc0[s][1][q];
            __syncthreads();
            {
                const float gi_ = sG[b_loc * 17 + jj]            + sG[128*17 + b_loc * 17 + jj]            + bias0[0];
                const float gf_ = sG[b_loc * 17 + 4 + jj]        + sG[128*17 + b_loc * 17 + 4 + jj]        + bias0[1];
                const float gg_ = sG[b_loc * 17 + 8 + jj]        + sG[128*17 + b_loc * 17 + 8 + jj]        + bias0[2];
                const float go_ = sG[b_loc * 17 + 12 + jj]       + sG[128*17 + b_loc * 17 + 12 + jj]       + bias0[3];
                const float iG = fsig(gi_);
                const float fG = fsig(gf_);
                const float gT = ftanh(gg_);
                const float oG = fsig(go_);
                c0 = fmaf(fG, c0, iG * gT);
                const float h = oG * ftanh(c0);
                store_h_pair(h0n, hoff, f2bf(h), l);
            }
            // ---- EARLY layer0-done signal: unblocks next iteration's wait-1
            asm volatile("s_waitcnt vmcnt(0)" ::: "memory");
            __syncthreads();
            if (tid == 0) st_u32_llc(f0g + jb, (unsigned)(it + 1));
        }

        // prefetch x[it+1]
        if (it + 1 < TT) {
            const float* sa = x + ((size_t)xrow0 * TT + (it + 1)) * DIN + kh * 32 + ks;
            const float* sb = x + ((size_t)(xrow0 + 16) * TT + (it + 1)) * DIN + kh * 32 + ks;
            *(float4*)&xva[0] = *(const float4*)sa;
            *(float4*)&xva[4] = *(const float4*)(sa + 4);
            *(float4*)&xvb[0] = *(const float4*)sb;
            *(float4*)&xvb[4] = *(const float4*)(sb + 4);
        }

        // ---- ys0-part of layer1: needs only fAh (guarded by wait-1) + static sW1.
        if (it > 0) {
            #pragma unroll
            for (int kt = 0; kt < 8; ++kt) {
                const int ktg = kh * 8 + kt;
                short8 bh = *(const short8*)&sW1h[(ktg * 64 + l) * 8];
                short8 bl = *(const short8*)&sW1l[(ktg * 64 + l) * 8];
                MFMA2(acc1[0][kt & 1], fAh[0][kt], bh, bl);
                MFMA2(acc1[1][kt & 1], fAh[1][kt], bh, bl);
            }
        }

        // ---- wait 2: layer1 of it-1 done everywhere (covers h1[it-2] writes)
        flag_wait(f1g, it);

        // ================= layer 1 (h1 half), t = it-1 =================
        if (it > 0) {
            short8 fCh[2][8];
            #pragma unroll
            for (int s = 0; s < 2; ++s)
                #pragma unroll
                for (int kt = 0; kt < 8; ++kt) {
                    const size_t o = (((size_t)(t0 + s) * 16 + kh * 8 + kt) * 64 + l) * 8;
                    fCh[s][kt] = *(const short8*)&h1c[o];
                }
            #pragma unroll
            for (int kt = 0; kt < 8; ++kt) {
                const int ktg = 16 + kh * 8 + kt;
                short8 bh = *(const short8*)&sW1h[(ktg * 64 + l) * 8];
                short8 bl = *(const short8*)&sW1l[(ktg * 64 + l) * 8];
                MFMA2(acc1[0][kt & 1], fCh[0][kt], bh, bl);
                MFMA2(acc1[1][kt & 1], fCh[1][kt], bh, bl);
            }
            #pragma unroll
            for (int s = 0; s < 2; ++s)
                #pragma unroll
                for (int q = 0; q < 4; ++q)
                    sGk[(bt2 * 32 + s * 16 + (l >> 4) * 4 + q) * 17 + (l & 15)]
                        = acc1[s][0][q] + acc1[s][1][q];
            __syncthreads();
            {
                const float gi_ = sG[b_loc * 17 + jj]            + sG[128*17 + b_loc * 17 + jj]            + bias1[0];
                const float gf_ = sG[b_loc * 17 + 4 + jj]        + sG[128*17 + b_loc * 17 + 4 + jj]        + bias1[1];
                const float gg_ = sG[b_loc * 17 + 8 + jj]        + sG[128*17 + b_loc * 17 + 8 + jj]        + bias1[2];
                const float go_ = sG[b_loc * 17 + 12 + jj]       + sG[128*17 + b_loc * 17 + 12 + jj]       + bias1[3];
                const float iG = fsig(gi_);
                const float fG = fsig(gf_);
                const float gT = ftanh(gg_);
                const float oG = fsig(go_);
                c1 = fmaf(fG, c1, iG * gT);
                const float h = oG * ftanh(c1);
                store_h_pair(h1n, hoff, f2bf(h), l);
            }
        }
        // ---- layer1-done signal + windowed fence (1/NSLOT iters, non-polling wave)
        asm volatile("s_waitcnt vmcnt(0)" ::: "memory");
        __syncthreads();
        if (tid == 0) st_u32_llc(f1g + jb, (unsigned)(it + 1));
        if ((it & 7) == 7 && tid >= 448)
            __builtin_amdgcn_fence(__ATOMIC_ACQUIRE, "agent");
    }

    // ---- head: out[b] = h1[TT-1] . w + b (slot 7; all layer1 done first)
    if (jb == 0) {
        if (tid < 128) {
            unsigned* p = f1g + tid;
            while ((int)ld_u32_llc(p) < TT + 1) __builtin_amdgcn_s_sleep(2);
        }
        __syncthreads();
        const unsigned short* h1h = h1base + (size_t)((TT + 7) & 7) * SLOT_SH;
        const int bl_ = tid >> 2;
        const int qd  = tid & 3;
        const int b   = g * 128 + bl_;
        const int btw = b >> 4;
        float s = 0.f;
        #pragma unroll
        for (int jt = qd * 4; jt < qd * 4 + 4; ++jt) {
            #pragma unroll
            for (int q2 = 0; q2 < 4; ++q2) {
                const size_t off = (((size_t)btw * 16 + jt) * 64 + ((b & 15) | (q2 << 4))) * 8;
                short8 vh = *(const short8*)&h1h[off];
                const int j0 = jt * 32 + q2 * 8;
                #pragma unroll
                for (int e = 0; e < 8; ++e)
                    s += bf2f((unsigned short)vh[e]) * headw[j0 + e];
            }
        }
        s += __shfl_down(s, 2, 4);
        s += __shfl_down(s, 1, 4);
        if (qd == 0) out[b] = s + headb[0];
    }
}

extern "C" void kernel_launch(void* const* d_in, const int* in_sizes, int n_in,
                              void* d_out, int out_size, void* d_ws, size_t ws_size,
                              hipStream_t stream) {
    const float* x      = (const float*)d_in[0];
    const float* W_ih0  = (const float*)d_in[1];
    const float* W_hh0  = (const float*)d_in[2];
    const float* b_ih0  = (const float*)d_in[3];
    const float* b_hh0  = (const float*)d_in[4];
    const float* W_ih1  = (const float*)d_in[5];
    const float* W_hh1  = (const float*)d_in[6];
    const float* b_ih1  = (const float*)d_in[7];
    const float* b_hh1  = (const float*)d_in[8];
    const float* head_w = (const float*)d_in[9];
    const float* head_b = (const float*)d_in[10];
    float* out = (float*)d_out;

    // ws layout: [flags 4KB (f0 g0,g1 | f1 g0,g1)][pad to 1MB][h0: 8x256KB][h1: 8x256KB]
    const size_t SLOT_BYTES = (size_t)SLOT_SH * 2;          // 256 KB
    unsigned* gf = (unsigned*)d_ws;
    unsigned short* h0base = (unsigned short*)((char*)d_ws + (1 << 20));
    unsigned short* h1base = (unsigned short*)((char*)d_ws + (1 << 20) + NSLOT * SLOT_BYTES);

    // zero: flags + the t=-1 slots (slot 7 of each chain)
    hipMemsetAsync(d_ws, 0, 4096, stream);
    hipMemsetAsync((char*)h0base + 7 * SLOT_BYTES, 0, SLOT_BYTES, stream);
    hipMemsetAsync((char*)h1base + 7 * SLOT_BYTES, 0, SLOT_BYTES, stream);

    hipFuncSetAttribute((const void*)lstm_persistent,
                        hipFuncAttributeMaxDynamicSharedMemorySize, LDS_BYTES);
    lstm_persistent<<<dim3(256), dim3(512), LDS_BYTES, stream>>>(
        x, W_ih0, W_hh0, b_ih0, b_hh0, W_ih1, W_hh1, b_ih1, b_hh1,
        head_w, head_b, h0base, h1base, gf, out);
}

// Round 16
// 1851.938 us; speedup vs baseline: 1.2765x; 1.2765x over previous
//
#include <hip/hip_runtime.h>

#define HID 512
#define NB  256
#define TT  256
#define DIN 64
#define HBUF 131072                  // shorts per h panel (bf16 hi only)
#define SLOT_SH HBUF                 // slot = one panel (256 KB)
#define NSLOT 8                      // rotation depth; fence every NSLOT iters

typedef __attribute__((ext_vector_type(8))) short short8;
typedef __attribute__((ext_vector_type(4))) float f32x4;

__device__ __forceinline__ unsigned short f2bf(float f) {
    unsigned int u = __float_as_uint(f);
    u += 0x7FFF + ((u >> 16) & 1);
    return (unsigned short)(u >> 16);
}
__device__ __forceinline__ float bf2f(unsigned short h) {
    return __uint_as_float(((unsigned int)h) << 16);
}

// fast activations: v_exp_f32 + v_rcp_f32 (error ~1e-6, budget 7.2e-4)
__device__ __forceinline__ float fsig(float x) {
    return __builtin_amdgcn_rcpf(1.f + __expf(-x));
}
__device__ __forceinline__ float ftanh(float x) {
    return 1.f - 2.f * __builtin_amdgcn_rcpf(1.f + __expf(2.f * x));
}

// ---- LLC-coherent (cross-XCD) 4B access, explicit sc0/sc1 cache bits ----
__device__ __forceinline__ void st_u32_llc(unsigned* p, unsigned v) {
    asm volatile("global_store_dword %0, %1, off sc0 sc1" :: "v"(p), "v"(v) : "memory");
}
__device__ __forceinline__ unsigned ld_u32_llc(const unsigned* p) {
    unsigned v;
    asm volatile("global_load_dword %0, %1, off sc0 sc1\n\ts_waitcnt vmcnt(0)"
                 : "=v"(v) : "v"(p) : "memory");
    return v;
}

// h-A operand is single bf16: 2-term split (A.Bh + A.Bl)
#define MFMA2(acc, a, bh, bl)                                               \
    acc = __builtin_amdgcn_mfma_f32_16x16x32_bf16(a, bh, acc, 0, 0, 0);     \
    acc = __builtin_amdgcn_mfma_f32_16x16x32_bf16(a, bl, acc, 0, 0, 0);
// x-A operand keeps hi/lo: 3-term split
#define MFMA3(acc, ah, al, bh, bl)                                          \
    acc = __builtin_amdgcn_mfma_f32_16x16x32_bf16(ah, bh, acc, 0, 0, 0);    \
    acc = __builtin_amdgcn_mfma_f32_16x16x32_bf16(ah, bl, acc, 0, 0, 0);    \
    acc = __builtin_amdgcn_mfma_f32_16x16x32_bf16(al, bh, acc, 0, 0, 0);

// LDS layout (shorts): sW0 h/l: 18*512 each; sW1 h/l: 32*512 each; then sG floats
#define SW0_N 9216
#define SW1_N 16384
#define SG_F (2 * 128 * 17)          // [kh][128 rows][17]
#define LDS_BYTES ((SW0_N * 2 + SW1_N * 2) * 2 + SG_F * 4)

// packed 2-lane h store: lanes (l, l+1) hold adjacent j; even lane stores u32
__device__ __forceinline__ void store_h_pair(unsigned short* buf, size_t hoff,
                                             unsigned short v, int l) {
    unsigned int hv = (unsigned int)v;
    unsigned int up = __shfl_down(hv, 1);
    if ((l & 1) == 0)
        st_u32_llc((unsigned*)(buf + hoff), hv | (up << 16));
}

// wait: 128 lanes poll one flag each (LLC loads, no cache pollution), then barrier
__device__ __forceinline__ void flag_wait(unsigned* fset, int target) {
    if (threadIdx.x < 128) {
        unsigned* p = fset + threadIdx.x;
        while ((int)ld_u32_llc(p) < target) __builtin_amdgcn_s_sleep(2);
    }
    __syncthreads();
}

__global__ __launch_bounds__(512, 2) void lstm_persistent(
    const float* __restrict__ x,
    const float* __restrict__ Wih0, const float* __restrict__ Whh0,
    const float* __restrict__ bih0, const float* __restrict__ bhh0,
    const float* __restrict__ Wih1, const float* __restrict__ Whh1,
    const float* __restrict__ bih1, const float* __restrict__ bhh1,
    const float* __restrict__ headw, const float* __restrict__ headb,
    unsigned short* h0base, unsigned short* h1base,
    unsigned* gf, float* __restrict__ out)
{
    extern __shared__ unsigned short lds[];
    unsigned short* sW0h = lds;
    unsigned short* sW0l = sW0h + SW0_N;
    unsigned short* sW1h = sW0l + SW0_N;
    unsigned short* sW1l = sW1h + SW1_N;
    float* sG = (float*)(sW1l + SW1_N);          // [2][128][17]

    const int tid = threadIdx.x;
    const int l   = tid & 63;
    const int w   = tid >> 6;         // wave 0..7
    const int bt2 = w & 3;            // batch-pair tile (32 rows)
    const int kh  = w >> 2;           // K-half (0: k<256, 1: k>=256)
    const int bid = blockIdx.x;
    const int g   = bid & 1;          // batch group
    const int jb  = bid >> 1;         // j-block 0..127 (hidden units jb*4..jb*4+3)

    unsigned* f0g = gf + g * 128;            // layer0-done flags (this group)
    unsigned* f1g = gf + 256 + g * 128;      // layer1-done flags (this group)

    // ---- weight preload: fp32 -> hi/lo bf16 fragments in LDS ----
    const int r  = l & 15;
    const int ks = (l >> 4) * 8;
    const int n  = (r >> 2) * HID + jb * 4 + (r & 3);
    {
        for (int kt = w; kt < 18; kt += 8) {
            const float* src = (kt < 2) ? (Wih0 + (size_t)n * DIN + kt * 32 + ks)
                                        : (Whh0 + (size_t)n * HID + (kt - 2) * 32 + ks);
            float v[8];
            *(float4*)&v[0] = *(const float4*)src;
            *(float4*)&v[4] = *(const float4*)(src + 4);
            union { unsigned short u[8]; uint4 q; } ph, pl;
            #pragma unroll
            for (int e = 0; e < 8; ++e) {
                unsigned short h = f2bf(v[e]);
                ph.u[e] = h; pl.u[e] = f2bf(v[e] - bf2f(h));
            }
            *(uint4*)&sW0h[(kt * 64 + l) * 8] = ph.q;
            *(uint4*)&sW0l[(kt * 64 + l) * 8] = pl.q;
        }
        for (int kt = w; kt < 32; kt += 8) {
            const float* src = (kt < 16) ? (Wih1 + (size_t)n * HID + kt * 32 + ks)
                                         : (Whh1 + (size_t)n * HID + (kt - 16) * 32 + ks);
            float v[8];
            *(float4*)&v[0] = *(const float4*)src;
            *(float4*)&v[4] = *(const float4*)(src + 4);
            union { unsigned short u[8]; uint4 q; } ph, pl;
            #pragma unroll
            for (int e = 0; e < 8; ++e) {
                unsigned short h = f2bf(v[e]);
                ph.u[e] = h; pl.u[e] = f2bf(v[e] - bf2f(h));
            }
            *(uint4*)&sW1h[(kt * 64 + l) * 8] = ph.q;
            *(uint4*)&sW1l[(kt * 64 + l) * 8] = pl.q;
        }
    }

    float bias0[4], bias1[4];
    #pragma unroll
    for (int gi = 0; gi < 4; ++gi) {
        const int nn = gi * HID + jb * 4 + (l & 3);
        bias0[gi] = bih0[nn] + bhh0[nn];
        bias1[gi] = bih1[nn] + bhh1[nn];
    }
    float c0 = 0.f, c1 = 0.f;

    // epilogue geometry (each thread owns one (b_loc, jj))
    const int jj     = tid & 3;
    const int b_loc  = tid >> 2;      // 0..127 within group
    const int b_glob = g * 128 + b_loc;
    const int j_glob = jb * 4 + jj;
    const size_t hoff = ((((size_t)(b_glob >> 4)) * 16 + (j_glob >> 5)) * 64
                         + ((b_glob & 15) | (((j_glob >> 3) & 3) << 4))) * 8 + (j_glob & 7);
    const int t0 = g * 8 + bt2 * 2;   // first 16-row tile of this wave's 32 rows

    // x prefetch registers: this wave's x-kt == kh, 2 tiles
    const int xrow0 = g * 128 + bt2 * 32 + (l & 15);
    float xva[8], xvb[8];
    {
        const float* sa = x + ((size_t)xrow0 * TT + 0) * DIN + kh * 32 + ks;
        const float* sb = x + ((size_t)(xrow0 + 16) * TT + 0) * DIN + kh * 32 + ks;
        *(float4*)&xva[0] = *(const float4*)sa;
        *(float4*)&xva[4] = *(const float4*)(sa + 4);
        *(float4*)&xvb[0] = *(const float4*)sb;
        *(float4*)&xvb[4] = *(const float4*)(sb + 4);
    }

    __syncthreads();                 // weights ready

    // x-part B fragments pinned in VGPRs (kt = kh, static)
    const short8 bxh = *(const short8*)&sW0h[(kh * 64 + l) * 8];
    const short8 bxl = *(const short8*)&sW0l[(kh * 64 + l) * 8];

    float* sGk = sG + kh * (128 * 17);

    for (int it = 0; it <= TT; ++it) {
        // ---- wait 1: layer0 of it-1 done everywhere (signaled MID-iteration -> fast)
        flag_wait(f0g, it);

        // slot map: h0[t] -> slot t&7 ; h1[t] -> slot t&7
        const unsigned short* h0c = h0base + (size_t)((it + 7) & 7) * SLOT_SH;  // h0[it-1]
        unsigned short* h0n       = h0base + (size_t)(it & 7) * SLOT_SH;        // h0[it]
        const unsigned short* h1c = h1base + (size_t)((it + 6) & 7) * SLOT_SH;  // h1[it-2]
        unsigned short* h1n       = h1base + (size_t)((it + 7) & 7) * SLOT_SH;  // h1[it-1]

        f32x4 acc0[2][2] = {{{0.f,0.f,0.f,0.f},{0.f,0.f,0.f,0.f}},
                            {{0.f,0.f,0.f,0.f},{0.f,0.f,0.f,0.f}}};
        f32x4 acc1[2][2] = {{{0.f,0.f,0.f,0.f},{0.f,0.f,0.f,0.f}},
                            {{0.f,0.f,0.f,0.f},{0.f,0.f,0.f,0.f}}};

        // ---- hoisted h0[it-1] A-fragments: 2 tiles x 8 kt (K-half), batched (MLP);
        // ---- used by layer0 (W0hh) AND layer1 ys0-part (W1ih)
        short8 fAh[2][8];
        #pragma unroll
        for (int s = 0; s < 2; ++s)
            #pragma unroll
            for (int kt = 0; kt < 8; ++kt) {
                const size_t o = (((size_t)(t0 + s) * 16 + kh * 8 + kt) * 64 + l) * 8;
                fAh[s][kt] = *(const short8*)&h0c[o];
            }

        // ================= layer 0, t = it =================
        if (it < TT) {
            // x part (kt = kh): pinned B regs, 2 tiles.
            // NOTE: accumulate into COMPILE-TIME index [0] (both halves are summed
            // at the sG write; runtime [kh] would force acc to scratch — rule #20).
            {
                union { unsigned short u[8]; short8 s8; } ah, al;
                #pragma unroll
                for (int e = 0; e < 8; ++e) {
                    unsigned short h = f2bf(xva[e]);
                    ah.u[e] = h; al.u[e] = f2bf(xva[e] - bf2f(h));
                }
                MFMA3(acc0[0][0], ah.s8, al.s8, bxh, bxl);
                #pragma unroll
                for (int e = 0; e < 8; ++e) {
                    unsigned short h = f2bf(xvb[e]);
                    ah.u[e] = h; al.u[e] = f2bf(xvb[e] - bf2f(h));
                }
                MFMA3(acc0[1][0], ah.s8, al.s8, bxh, bxl);
            }
            // h part: 8 kt, B reused across 2 batch tiles
            #pragma unroll
            for (int kt = 0; kt < 8; ++kt) {
                const int ktg = kh * 8 + kt;
                short8 bh = *(const short8*)&sW0h[((ktg + 2) * 64 + l) * 8];
                short8 bl = *(const short8*)&sW0l[((ktg + 2) * 64 + l) * 8];
                MFMA2(acc0[0][kt & 1], fAh[0][kt], bh, bl);
                MFMA2(acc0[1][kt & 1], fAh[1][kt], bh, bl);
            }
            // write K-half partials to own sG half
            #pragma unroll
            for (int s = 0; s < 2; ++s)
                #pragma unroll
                for (int q = 0; q < 4; ++q)
                    sGk[(bt2 * 32 + s * 16 + (l >> 4) * 4 + q) * 17 + (l & 15)]
                        = acc0[s][0][q] + acc0[s][1][q];
            __syncthreads();
            {
                const float gi_ = sG[b_loc * 17 + jj]      + sG[128*17 + b_loc * 17 + jj]      + bias0[0];
                const float gf_ = sG[b_loc * 17 + 4 + jj]  + sG[128*17 + b_loc * 17 + 4 + jj]  + bias0[1];
                const float gg_ = sG[b_loc * 17 + 8 + jj]  + sG[128*17 + b_loc * 17 + 8 + jj]  + bias0[2];
                const float go_ = sG[b_loc * 17 + 12 + jj] + sG[128*17 + b_loc * 17 + 12 + jj] + bias0[3];
                const float iG = fsig(gi_);
                const float fG = fsig(gf_);
                const float gT = ftanh(gg_);
                const float oG = fsig(go_);
                c0 = fmaf(fG, c0, iG * gT);
                const float h = oG * ftanh(c0);
                store_h_pair(h0n, hoff, f2bf(h), l);
            }
            // ---- EARLY layer0-done signal: unblocks next iteration's wait-1
            asm volatile("s_waitcnt vmcnt(0)" ::: "memory");
            __syncthreads();
            if (tid == 0) st_u32_llc(f0g + jb, (unsigned)(it + 1));
        }

        // prefetch x[it+1]
        if (it + 1 < TT) {
            const float* sa = x + ((size_t)xrow0 * TT + (it + 1)) * DIN + kh * 32 + ks;
            const float* sb = x + ((size_t)(xrow0 + 16) * TT + (it + 1)) * DIN + kh * 32 + ks;
            *(float4*)&xva[0] = *(const float4*)sa;
            *(float4*)&xva[4] = *(const float4*)(sa + 4);
            *(float4*)&xvb[0] = *(const float4*)sb;
            *(float4*)&xvb[4] = *(const float4*)(sb + 4);
        }

        // ---- ys0-part of layer1: needs only fAh (guarded by wait-1) + static sW1.
        if (it > 0) {
            #pragma unroll
            for (int kt = 0; kt < 8; ++kt) {
                const int ktg = kh * 8 + kt;
                short8 bh = *(const short8*)&sW1h[(ktg * 64 + l) * 8];
                short8 bl = *(const short8*)&sW1l[(ktg * 64 + l) * 8];
                MFMA2(acc1[0][kt & 1], fAh[0][kt], bh, bl);
                MFMA2(acc1[1][kt & 1], fAh[1][kt], bh, bl);
            }
        }

        // ---- wait 2: layer1 of it-1 done everywhere (covers h1[it-2] writes)
        flag_wait(f1g, it);

        // ================= layer 1 (h1 half), t = it-1 =================
        if (it > 0) {
            short8 fCh[2][8];
            #pragma unroll
            for (int s = 0; s < 2; ++s)
                #pragma unroll
                for (int kt = 0; kt < 8; ++kt) {
                    const size_t o = (((size_t)(t0 + s) * 16 + kh * 8 + kt) * 64 + l) * 8;
                    fCh[s][kt] = *(const short8*)&h1c[o];
                }
            #pragma unroll
            for (int kt = 0; kt < 8; ++kt) {
                const int ktg = 16 + kh * 8 + kt;
                short8 bh = *(const short8*)&sW1h[(ktg * 64 + l) * 8];
                short8 bl = *(const short8*)&sW1l[(ktg * 64 + l) * 8];
                MFMA2(acc1[0][kt & 1], fCh[0][kt], bh, bl);
                MFMA2(acc1[1][kt & 1], fCh[1][kt], bh, bl);
            }
            #pragma unroll
            for (int s = 0; s < 2; ++s)
                #pragma unroll
                for (int q = 0; q < 4; ++q)
                    sGk[(bt2 * 32 + s * 16 + (l >> 4) * 4 + q) * 17 + (l & 15)]
                        = acc1[s][0][q] + acc1[s][1][q];
            __syncthreads();
            {
                const float gi_ = sG[b_loc * 17 + jj]      + sG[128*17 + b_loc * 17 + jj]      + bias1[0];
                const float gf_ = sG[b_loc * 17 + 4 + jj]  + sG[128*17 + b_loc * 17 + 4 + jj]  + bias1[1];
                const float gg_ = sG[b_loc * 17 + 8 + jj]  + sG[128*17 + b_loc * 17 + 8 + jj]  + bias1[2];
                const float go_ = sG[b_loc * 17 + 12 + jj] + sG[128*17 + b_loc * 17 + 12 + jj] + bias1[3];
                const float iG = fsig(gi_);
                const float fG = fsig(gf_);
                const float gT = ftanh(gg_);
                const float oG = fsig(go_);
                c1 = fmaf(fG, c1, iG * gT);
                const float h = oG * ftanh(c1);
                store_h_pair(h1n, hoff, f2bf(h), l);
            }
        }
        // ---- layer1-done signal + windowed fence (1/NSLOT iters, non-polling wave)
        asm volatile("s_waitcnt vmcnt(0)" ::: "memory");
        __syncthreads();
        if (tid == 0) st_u32_llc(f1g + jb, (unsigned)(it + 1));
        if ((it & 7) == 7 && tid >= 448)
            __builtin_amdgcn_fence(__ATOMIC_ACQUIRE, "agent");
    }

    // ---- head: out[b] = h1[TT-1] . w + b (slot 7; all layer1 done first)
    if (jb == 0) {
        if (tid < 128) {
            unsigned* p = f1g + tid;
            while ((int)ld_u32_llc(p) < TT + 1) __builtin_amdgcn_s_sleep(2);
        }
        __syncthreads();
        const unsigned short* h1h = h1base + (size_t)((TT + 7) & 7) * SLOT_SH;
        const int bl_ = tid >> 2;
        const int qd  = tid & 3;
        const int b   = g * 128 + bl_;
        const int btw = b >> 4;
        float s = 0.f;
        #pragma unroll
        for (int jt = qd * 4; jt < qd * 4 + 4; ++jt) {
            #pragma unroll
            for (int q2 = 0; q2 < 4; ++q2) {
                const size_t off = (((size_t)btw * 16 + jt) * 64 + ((b & 15) | (q2 << 4))) * 8;
                short8 vh = *(const short8*)&h1h[off];
                const int j0 = jt * 32 + q2 * 8;
                #pragma unroll
                for (int e = 0; e < 8; ++e)
                    s += bf2f((unsigned short)vh[e]) * headw[j0 + e];
            }
        }
        s += __shfl_down(s, 2, 4);
        s += __shfl_down(s, 1, 4);
        if (qd == 0) out[b] = s + headb[0];
    }
}

extern "C" void kernel_launch(void* const* d_in, const int* in_sizes, int n_in,
                              void* d_out, int out_size, void* d_ws, size_t ws_size,
                              hipStream_t stream) {
    const float* x      = (const float*)d_in[0];
    const float* W_ih0  = (const float*)d_in[1];
    const float* W_hh0  = (const float*)d_in[2];
    const float* b_ih0  = (const float*)d_in[3];
    const float* b_hh0  = (const float*)d_in[4];
    const float* W_ih1  = (const float*)d_in[5];
    const float* W_hh1  = (const float*)d_in[6];
    const float* b_ih1  = (const float*)d_in[7];
    const float* b_hh1  = (const float*)d_in[8];
    const float* head_w = (const float*)d_in[9];
    const float* head_b = (const float*)d_in[10];
    float* out = (float*)d_out;

    // ws layout: [flags 4KB (f0 g0,g1 | f1 g0,g1)][pad to 1MB][h0: 8x256KB][h1: 8x256KB]
    const size_t SLOT_BYTES = (size_t)SLOT_SH * 2;          // 256 KB
    unsigned* gf = (unsigned*)d_ws;
    unsigned short* h0base = (unsigned short*)((char*)d_ws + (1 << 20));
    unsigned short* h1base = (unsigned short*)((char*)d_ws + (1 << 20) + NSLOT * SLOT_BYTES);

    // zero: flags + the t=-1 slots (slot 7 of each chain)
    hipMemsetAsync(d_ws, 0, 4096, stream);
    hipMemsetAsync((char*)h0base + 7 * SLOT_BYTES, 0, SLOT_BYTES, stream);
    hipMemsetAsync((char*)h1base + 7 * SLOT_BYTES, 0, SLOT_BYTES, stream);

    hipFuncSetAttribute((const void*)lstm_persistent,
                        hipFuncAttributeMaxDynamicSharedMemorySize, LDS_BYTES);
    lstm_persistent<<<dim3(256), dim3(512), LDS_BYTES, stream>>>(
        x, W_ih0, W_hh0, b_ih0, b_hh0, W_ih1, W_hh1, b_ih1, b_hh1,
        head_w, head_b, h0base, h1base, gf, out);
}